// Round 9
// baseline (137.288 us; speedup 1.0000x reference)
//
#include <hip/hip_runtime.h>

#define H     256
#define BM    128
#define NTHR  1024
#define LDK2  264    // 256 + 8 pad (ushorts): row stride 528 B

typedef __attribute__((ext_vector_type(4))) float f32x4;
typedef __attribute__((ext_vector_type(8))) short bf16x8;

__device__ __forceinline__ ushort f2bf(float f) {
    union { float f; unsigned u; } v; v.f = f;
    unsigned u = v.u;
    unsigned r = (u + 0x7fffu + ((u >> 16) & 1u)) >> 16;
    return (ushort)r;
}
__device__ __forceinline__ float bf2f(ushort h) {
    union { unsigned u; float f; } v; v.u = ((unsigned)h) << 16;
    return v.f;
}
__device__ __forceinline__ float sigmoid_f(float x) {
    return __builtin_amdgcn_rcpf(1.0f + __expf(-x));
}
__device__ __forceinline__ float tanh_f(float x) {
    float ax = fabsf(x);
    float e  = __expf(-2.0f * ax);
    float t  = (1.0f - e) * __builtin_amdgcn_rcpf(1.0f + e);
    return copysignf(t, x);
}

// --- weight prep: f32 [k][n] -> bf16 panels [n][k] in d_ws ---
// rows 0..255 = r cols (k<256: W_r, k>=256: U_r); 256..511 = z; 512..767 = h
__global__ void prep_w(const float* __restrict__ Wr, const float* __restrict__ Wz,
                       const float* __restrict__ Wh, const float* __restrict__ Ur,
                       const float* __restrict__ Uz, const float* __restrict__ Uh,
                       ushort* __restrict__ P)
{
    const int k  = blockIdx.x;          // 0..511
    const int kk = k & 255;
    const bool hi = k >= 256;
    for (int n = threadIdx.x; n < 768; n += 256) {
        float v;
        if (n < 256)      v = (hi ? Ur : Wr)[kk * 256 + n];
        else if (n < 512) v = (hi ? Uz : Wz)[kk * 256 + (n - 256)];
        else              v = (hi ? Uh : Wh)[kk * 256 + (n - 512)];
        P[(size_t)n * 512 + k] = f2bf(v);
    }
}

#define MFMA(a, b, c) __builtin_amdgcn_mfma_f32_16x16x32_bf16((a), (b), (c), 0, 0, 0)

// one 16x16x32 k-step over r|z accumulators (wave tile 64 rows x 32 cols)
// SB: LDS A-buffer; K0: k-offset in LDS (0..224); KOFF: 0 (W) or 256 (U) for B
#define RZ_STEP(SB, K0, KOFF) do {                                            \
    bf16x8 bR_[2], bZ_[2];                                                    \
    bR_[0] = *(const bf16x8*)(pBr + (KOFF) + (K0));                           \
    bR_[1] = *(const bf16x8*)(pBr + (size_t)16 * 512 + (KOFF) + (K0));        \
    bZ_[0] = *(const bf16x8*)(pBz + (KOFF) + (K0));                           \
    bZ_[1] = *(const bf16x8*)(pBz + (size_t)16 * 512 + (KOFF) + (K0));        \
    _Pragma("unroll") for (int ip_ = 0; ip_ < 2; ++ip_) {                     \
        bf16x8 a0_ = *(const bf16x8*)&SB[(rowbase + (ip_ * 2 + 0) * 16 + l15) * LDK2 + (K0) + kq * 8]; \
        bf16x8 a1_ = *(const bf16x8*)&SB[(rowbase + (ip_ * 2 + 1) * 16 + l15) * LDK2 + (K0) + kq * 8]; \
        aR[ip_ * 2 + 0][0] = MFMA(a0_, bR_[0], aR[ip_ * 2 + 0][0]);           \
        aR[ip_ * 2 + 1][0] = MFMA(a1_, bR_[0], aR[ip_ * 2 + 1][0]);           \
        aZ[ip_ * 2 + 0][0] = MFMA(a0_, bZ_[0], aZ[ip_ * 2 + 0][0]);           \
        aZ[ip_ * 2 + 1][0] = MFMA(a1_, bZ_[0], aZ[ip_ * 2 + 1][0]);           \
        aR[ip_ * 2 + 0][1] = MFMA(a0_, bR_[1], aR[ip_ * 2 + 0][1]);           \
        aR[ip_ * 2 + 1][1] = MFMA(a1_, bR_[1], aR[ip_ * 2 + 1][1]);           \
        aZ[ip_ * 2 + 0][1] = MFMA(a0_, bZ_[1], aZ[ip_ * 2 + 0][1]);           \
        aZ[ip_ * 2 + 1][1] = MFMA(a1_, bZ_[1], aZ[ip_ * 2 + 1][1]);           \
    }                                                                         \
} while (0)

#define H_STEP(SB, K0, KOFF) do {                                             \
    bf16x8 bH_[2];                                                            \
    bH_[0] = *(const bf16x8*)(pBh + (KOFF) + (K0));                           \
    bH_[1] = *(const bf16x8*)(pBh + (size_t)16 * 512 + (KOFF) + (K0));        \
    _Pragma("unroll") for (int ip_ = 0; ip_ < 2; ++ip_) {                     \
        bf16x8 a0_ = *(const bf16x8*)&SB[(rowbase + (ip_ * 2 + 0) * 16 + l15) * LDK2 + (K0) + kq * 8]; \
        bf16x8 a1_ = *(const bf16x8*)&SB[(rowbase + (ip_ * 2 + 1) * 16 + l15) * LDK2 + (K0) + kq * 8]; \
        aH[ip_ * 2 + 0][0] = MFMA(a0_, bH_[0], aH[ip_ * 2 + 0][0]);           \
        aH[ip_ * 2 + 1][0] = MFMA(a1_, bH_[0], aH[ip_ * 2 + 1][0]);           \
        aH[ip_ * 2 + 0][1] = MFMA(a0_, bH_[1], aH[ip_ * 2 + 0][1]);           \
        aH[ip_ * 2 + 1][1] = MFMA(a1_, bH_[1], aH[ip_ * 2 + 1][1]);           \
    }                                                                         \
} while (0)

// joint staging pipeline into sb1 (separate buffer -> no race with sb0 reads)
#define LOADJ(JV, CI) do {                                                    \
    _Pragma("unroll") for (int i_ = 0; i_ < 2; ++i_) {                        \
        const int c_ = tid + ((CI) * 2 + i_) * NTHR;                          \
        JV[i_] = *(const f32x4*)(joint + (r0 + (c_ >> 6)) * H + (c_ & 63) * 4); \
    }                                                                         \
} while (0)

#define COMMITJ(JV, CI) do {                                                  \
    _Pragma("unroll") for (int i_ = 0; i_ < 2; ++i_) {                        \
        const int c_ = tid + ((CI) * 2 + i_) * NTHR;                          \
        ushort4 w_;                                                           \
        w_.x = f2bf(JV[i_][0]); w_.y = f2bf(JV[i_][1]);                       \
        w_.z = f2bf(JV[i_][2]); w_.w = f2bf(JV[i_][3]);                       \
        *(ushort4*)&sb1[(c_ >> 6) * LDK2 + (c_ & 63) * 4] = w_;               \
    }                                                                         \
} while (0)

__global__ __launch_bounds__(NTHR, 4)
void gru_main(const float* __restrict__ joint, const float* __restrict__ mgn,
              const ushort* __restrict__ P,
              const float* __restrict__ br_, const float* __restrict__ bz_,
              const float* __restrict__ bh_, float* __restrict__ out)
{
    __shared__ ushort sb0[BM * LDK2];   // mgn bf16 — resident for the whole kernel
    __shared__ ushort sb1[BM * LDK2];   // joint bf16 -> overwritten by a = joint*r

    const int tid  = threadIdx.x;
    const int wave = tid >> 6;          // 0..15
    const int lane = tid & 63;
    const int l15  = lane & 15;
    const int kq   = lane >> 4;         // 0..3
    const int rowbase = (wave >> 3) * 64;   // 2 row-groups of 64
    const int colbase = (wave & 7) * 32;    // 8 col-groups of 32
    const size_t r0 = (size_t)blockIdx.x * BM;

    const ushort* __restrict__ pBr = P + (size_t)(colbase + l15) * 512 + kq * 8;
    const ushort* __restrict__ pBz = pBr + (size_t)256 * 512;
    const ushort* __restrict__ pBh = pBr + (size_t)512 * 512;

    // --- stage 0: mgn -> sb0 (kernel head) ---
    #pragma unroll
    for (int i = 0; i < 8; ++i) {
        const int c   = tid + i * NTHR;
        const int row = c >> 6;
        const int c4  = (c & 63) * 4;
        const f32x4 v = *(const f32x4*)(mgn + (r0 + row) * H + c4);
        ushort4 w;
        w.x = f2bf(v[0]); w.y = f2bf(v[1]); w.z = f2bf(v[2]); w.w = f2bf(v[3]);
        *(ushort4*)&sb0[row * LDK2 + c4] = w;
    }
    __syncthreads();

    f32x4 aR[4][2], aZ[4][2];
    #pragma unroll
    for (int i = 0; i < 4; ++i)
        #pragma unroll
        for (int j = 0; j < 2; ++j) {
            aR[i][j] = (f32x4){0.f, 0.f, 0.f, 0.f};
            aZ[i][j] = (f32x4){0.f, 0.f, 0.f, 0.f};
        }

    // --- phase 1, k-half 0 (mgn in sb0); joint -> sb1 pipelined in 8-reg chunks ---
    {
        f32x4 jv[2];
        LOADJ(jv, 0);
        RZ_STEP(sb0, 0, 0);   RZ_STEP(sb0, 32, 0);
        COMMITJ(jv, 0);  LOADJ(jv, 1);
        RZ_STEP(sb0, 64, 0);  RZ_STEP(sb0, 96, 0);
        COMMITJ(jv, 1);  LOADJ(jv, 2);
        RZ_STEP(sb0, 128, 0); RZ_STEP(sb0, 160, 0);
        COMMITJ(jv, 2);  LOADJ(jv, 3);
        RZ_STEP(sb0, 192, 0); RZ_STEP(sb0, 224, 0);
        COMMITJ(jv, 3);
    }
    __syncthreads();    // joint fully staged in sb1

    // --- phase 1, k-half 1 (joint in sb1) ---
    #pragma unroll 2
    for (int k0 = 0; k0 < 256; k0 += 32) RZ_STEP(sb1, k0, 256);
    __syncthreads();

    // --- gates: z kept in aZ regs; a = joint*r overwrites sb1 in place ---
    {
        float br[2], bz[2];
        #pragma unroll
        for (int j = 0; j < 2; ++j) {
            const int c = colbase + j * 16 + l15;
            br[j] = br_[c]; bz[j] = bz_[c];
        }
        #pragma unroll
        for (int i = 0; i < 4; ++i)
            #pragma unroll
            for (int j = 0; j < 2; ++j)
                #pragma unroll
                for (int q = 0; q < 4; ++q) {
                    const int row = rowbase + i * 16 + kq * 4 + q;
                    const int c   = colbase + j * 16 + l15;
                    const float r = sigmoid_f(aR[i][j][q] + br[j]);
                    const float hj = bf2f(sb1[row * LDK2 + c]);
                    sb1[row * LDK2 + c] = f2bf(hj * r);
                    aZ[i][j][q] = sigmoid_f(aZ[i][j][q] + bz[j]);
                }
    }
    __syncthreads();

    // --- phase 2: ht = [mgn | a] @ P_h — both halves resident, no staging ---
    f32x4 aH[4][2];
    #pragma unroll
    for (int i = 0; i < 4; ++i)
        #pragma unroll
        for (int j = 0; j < 2; ++j)
            aH[i][j] = (f32x4){0.f, 0.f, 0.f, 0.f};

    #pragma unroll 2
    for (int k0 = 0; k0 < 256; k0 += 32) H_STEP(sb1, k0, 256);
    #pragma unroll 2
    for (int k0 = 0; k0 < 256; k0 += 32) H_STEP(sb0, k0, 0);

    // --- epilogue: out = ht + z*(h - ht), h re-read f32 (L3-warm) ---
    {
        float bh[2];
        #pragma unroll
        for (int j = 0; j < 2; ++j) bh[j] = bh_[colbase + j * 16 + l15];
        #pragma unroll
        for (int i = 0; i < 4; ++i)
            #pragma unroll
            for (int j = 0; j < 2; ++j)
                #pragma unroll
                for (int q = 0; q < 4; ++q) {
                    const int row = rowbase + i * 16 + kq * 4 + q;
                    const int c   = colbase + j * 16 + l15;
                    const float ht = tanh_f(aH[i][j][q] + bh[j]);
                    const float z  = aZ[i][j][q];
                    const float h  = joint[(r0 + row) * H + c];
                    out[(r0 + row) * H + c] = ht + z * (h - ht);
                }
    }
}

extern "C" void kernel_launch(void* const* d_in, const int* in_sizes, int n_in,
                              void* d_out, int out_size, void* d_ws, size_t ws_size,
                              hipStream_t stream)
{
    const float* joint = (const float*)d_in[0];
    const float* mgn   = (const float*)d_in[1];
    const float* Wr    = (const float*)d_in[2];
    const float* Wz    = (const float*)d_in[3];
    const float* Wh    = (const float*)d_in[4];
    const float* Ur    = (const float*)d_in[5];
    const float* Uz    = (const float*)d_in[6];
    const float* Uh    = (const float*)d_in[7];
    const float* br    = (const float*)d_in[8];
    const float* bz    = (const float*)d_in[9];
    const float* bh    = (const float*)d_in[10];

    ushort* P  = (ushort*)d_ws;          // 786 KB scratch
    float* out = (float*)d_out;

    prep_w<<<512, 256, 0, stream>>>(Wr, Wz, Wh, Ur, Uz, Uh, P);

    const int nrows = 65536;
    gru_main<<<nrows / BM, NTHR, 0, stream>>>(joint, mgn, P, br, bz, bh, out);
}

// Round 10
// 118.748 us; speedup vs baseline: 1.1561x; 1.1561x over previous
//
#include <hip/hip_runtime.h>

#define H     256
#define BM    128
#define NTHR  512
#define LDK2  264    // 256 + 8 pad (ushorts): row stride 528 B

typedef __attribute__((ext_vector_type(4))) float f32x4;
typedef __attribute__((ext_vector_type(8))) short bf16x8;

__device__ __forceinline__ ushort f2bf(float f) {
    union { float f; unsigned u; } v; v.f = f;
    unsigned u = v.u;
    unsigned r = (u + 0x7fffu + ((u >> 16) & 1u)) >> 16;
    return (ushort)r;
}
__device__ __forceinline__ float bf2f(ushort h) {
    union { unsigned u; float f; } v; v.u = ((unsigned)h) << 16;
    return v.f;
}
__device__ __forceinline__ float sigmoid_f(float x) {
    return __builtin_amdgcn_rcpf(1.0f + __expf(-x));
}
__device__ __forceinline__ float tanh_f(float x) {
    float ax = fabsf(x);
    float e  = __expf(-2.0f * ax);
    float t  = (1.0f - e) * __builtin_amdgcn_rcpf(1.0f + e);
    return copysignf(t, x);
}

// --- weight prep: f32 [k][n] -> bf16 panels [n][k] in d_ws ---
// rows 0..255 = r cols (k<256: W_r, k>=256: U_r); 256..511 = z; 512..767 = h
__global__ void prep_w(const float* __restrict__ Wr, const float* __restrict__ Wz,
                       const float* __restrict__ Wh, const float* __restrict__ Ur,
                       const float* __restrict__ Uz, const float* __restrict__ Uh,
                       ushort* __restrict__ P)
{
    const int k  = blockIdx.x;          // 0..511
    const int kk = k & 255;
    const bool hi = k >= 256;
    for (int n = threadIdx.x; n < 768; n += 256) {
        float v;
        if (n < 256)      v = (hi ? Ur : Wr)[kk * 256 + n];
        else if (n < 512) v = (hi ? Uz : Wz)[kk * 256 + (n - 256)];
        else              v = (hi ? Uh : Wh)[kk * 256 + (n - 512)];
        P[(size_t)n * 512 + k] = f2bf(v);
    }
}

#define MFMA(a, b, c) __builtin_amdgcn_mfma_f32_16x16x32_bf16((a), (b), (c), 0, 0, 0)

// ---- phase-1 (r|z) pipeline pieces: step S in [0,16); S<8 -> sb0/W, S>=8 -> sb1/U
#define LOADB_RZ(S, BR, BZ) do {                                              \
    const int ko_ = (((S) < 8) ? 0 : 256) + ((S) & 7) * 32;                   \
    BR[0] = *(const bf16x8*)(pBr + ko_);                                      \
    BR[1] = *(const bf16x8*)(pBr + (size_t)16 * 512 + ko_);                   \
    BZ[0] = *(const bf16x8*)(pBz + ko_);                                      \
    BZ[1] = *(const bf16x8*)(pBz + (size_t)16 * 512 + ko_);                   \
} while (0)

#define STEP_RZ(S, BR, BZ) do {                                               \
    const ushort* sb_ = ((S) < 8) ? sb0 : sb1;                                \
    const int k0_ = ((S) & 7) * 32;                                           \
    bf16x8 af_[8];                                                            \
    _Pragma("unroll") for (int i_ = 0; i_ < 8; ++i_)                          \
        af_[i_] = *(const bf16x8*)&sb_[(i_ * 16 + l15) * LDK2 + k0_ + kq * 8];\
    _Pragma("unroll") for (int j_ = 0; j_ < 2; ++j_)                          \
    _Pragma("unroll") for (int i_ = 0; i_ < 8; ++i_) {                        \
        aR[i_][j_] = MFMA(af_[i_], BR[j_], aR[i_][j_]);                       \
        aZ[i_][j_] = MFMA(af_[i_], BZ[j_], aZ[i_][j_]);                       \
    }                                                                         \
} while (0)

// ---- phase-2 (h) pipeline pieces: S<8 -> sb1/U_h (a), S>=8 -> sb0/W_h (mgn)
#define LOADB_H(S, BH) do {                                                   \
    const int ko_ = (((S) < 8) ? 256 : 0) + ((S) & 7) * 32;                   \
    BH[0] = *(const bf16x8*)(pBh + ko_);                                      \
    BH[1] = *(const bf16x8*)(pBh + (size_t)16 * 512 + ko_);                   \
} while (0)

#define STEP_H(S, BH) do {                                                    \
    const ushort* sb_ = ((S) < 8) ? sb1 : sb0;                                \
    const int k0_ = ((S) & 7) * 32;                                           \
    bf16x8 af_[8];                                                            \
    _Pragma("unroll") for (int i_ = 0; i_ < 8; ++i_)                          \
        af_[i_] = *(const bf16x8*)&sb_[(i_ * 16 + l15) * LDK2 + k0_ + kq * 8];\
    _Pragma("unroll") for (int j_ = 0; j_ < 2; ++j_)                          \
    _Pragma("unroll") for (int i_ = 0; i_ < 8; ++i_)                          \
        aH[i_][j_] = MFMA(af_[i_], BH[j_], aH[i_][j_]);                       \
} while (0)

// ---- joint staging: 4-f32x4 chunks, load early / commit ~2 k-steps later
#define LOADJ(CI) do {                                                        \
    _Pragma("unroll") for (int i_ = 0; i_ < 4; ++i_) {                        \
        const int c_ = tid + ((CI) * 4 + i_) * NTHR;                          \
        jv[i_] = *(const f32x4*)(joint + (r0 + (c_ >> 6)) * H + (c_ & 63) * 4); \
    }                                                                         \
} while (0)

#define COMMITJ(CI) do {                                                      \
    _Pragma("unroll") for (int i_ = 0; i_ < 4; ++i_) {                        \
        const int c_ = tid + ((CI) * 4 + i_) * NTHR;                          \
        ushort4 w_;                                                           \
        w_.x = f2bf(jv[i_][0]); w_.y = f2bf(jv[i_][1]);                       \
        w_.z = f2bf(jv[i_][2]); w_.w = f2bf(jv[i_][3]);                       \
        *(ushort4*)&sb1[(c_ >> 6) * LDK2 + (c_ & 63) * 4] = w_;               \
    }                                                                         \
} while (0)

__global__ __launch_bounds__(NTHR, 2)
void gru_main(const float* __restrict__ joint, const float* __restrict__ mgn,
              const ushort* __restrict__ P,
              const float* __restrict__ br_, const float* __restrict__ bz_,
              const float* __restrict__ bh_, float* __restrict__ out)
{
    __shared__ ushort sb0[BM * LDK2];   // mgn bf16 — resident whole kernel
    __shared__ ushort sb1[BM * LDK2];   // joint bf16 -> overwritten by a = joint*r

    const int tid  = threadIdx.x;
    const int wave = tid >> 6;          // 0..7
    const int lane = tid & 63;
    const int l15  = lane & 15;
    const int kq   = lane >> 4;         // 0..3
    const int colbase = wave * 32;      // each B row read by exactly one wave
    const size_t r0 = (size_t)blockIdx.x * BM;

    const ushort* __restrict__ pBr = P + (size_t)(colbase + l15) * 512 + kq * 8;
    const ushort* __restrict__ pBz = pBr + (size_t)256 * 512;
    const ushort* __restrict__ pBh = pBr + (size_t)512 * 512;

    // --- stage 0: mgn -> sb0 ---
    #pragma unroll
    for (int i = 0; i < 16; ++i) {
        const int c   = tid + i * NTHR;
        const int row = c >> 6;
        const int c4  = (c & 63) * 4;
        const f32x4 v = *(const f32x4*)(mgn + (r0 + row) * H + c4);
        ushort4 w;
        w.x = f2bf(v[0]); w.y = f2bf(v[1]); w.z = f2bf(v[2]); w.w = f2bf(v[3]);
        *(ushort4*)&sb0[row * LDK2 + c4] = w;
    }
    __syncthreads();

    f32x4 aR[8][2], aZ[8][2];
    #pragma unroll
    for (int i = 0; i < 8; ++i)
        #pragma unroll
        for (int j = 0; j < 2; ++j) {
            aR[i][j] = (f32x4){0.f, 0.f, 0.f, 0.f};
            aZ[i][j] = (f32x4){0.f, 0.f, 0.f, 0.f};
        }

    // --- phase 1: 16 k-steps, depth-2 rolling B prefetch; joint->sb1 staged in 4 chunks ---
    {
        f32x4 jv[4];
        bf16x8 bRA[2], bZA[2], bRB[2], bZB[2];
        LOADB_RZ(0, bRA, bZA);
        LOADB_RZ(1, bRB, bZB);
        LOADJ(0);
        STEP_RZ(0, bRA, bZA);  LOADB_RZ(2, bRA, bZA);
        STEP_RZ(1, bRB, bZB);  LOADB_RZ(3, bRB, bZB);
        COMMITJ(0); LOADJ(1);
        STEP_RZ(2, bRA, bZA);  LOADB_RZ(4, bRA, bZA);
        STEP_RZ(3, bRB, bZB);  LOADB_RZ(5, bRB, bZB);
        COMMITJ(1); LOADJ(2);
        STEP_RZ(4, bRA, bZA);  LOADB_RZ(6, bRA, bZA);
        STEP_RZ(5, bRB, bZB);  LOADB_RZ(7, bRB, bZB);
        COMMITJ(2); LOADJ(3);
        STEP_RZ(6, bRA, bZA);  LOADB_RZ(8, bRA, bZA);
        STEP_RZ(7, bRB, bZB);  LOADB_RZ(9, bRB, bZB);
        COMMITJ(3);
        __syncthreads();        // sb1 (joint) ready; sb0 reads done
        STEP_RZ(8, bRA, bZA);  LOADB_RZ(10, bRA, bZA);
        STEP_RZ(9, bRB, bZB);  LOADB_RZ(11, bRB, bZB);
        STEP_RZ(10, bRA, bZA); LOADB_RZ(12, bRA, bZA);
        STEP_RZ(11, bRB, bZB); LOADB_RZ(13, bRB, bZB);
        STEP_RZ(12, bRA, bZA); LOADB_RZ(14, bRA, bZA);
        STEP_RZ(13, bRB, bZB); LOADB_RZ(15, bRB, bZB);
        STEP_RZ(14, bRA, bZA);
        STEP_RZ(15, bRB, bZB);
    }
    __syncthreads();

    // --- gates: z kept in aZ regs; a = joint*r overwrites sb1 in place ---
    {
        float br[2], bz[2];
        #pragma unroll
        for (int j = 0; j < 2; ++j) {
            const int c = colbase + j * 16 + l15;
            br[j] = br_[c]; bz[j] = bz_[c];
        }
        #pragma unroll
        for (int i = 0; i < 8; ++i)
            #pragma unroll
            for (int j = 0; j < 2; ++j)
                #pragma unroll
                for (int q = 0; q < 4; ++q) {
                    const int row = i * 16 + kq * 4 + q;
                    const int c   = colbase + j * 16 + l15;
                    const float r = sigmoid_f(aR[i][j][q] + br[j]);
                    const float hj = bf2f(sb1[row * LDK2 + c]);
                    sb1[row * LDK2 + c] = f2bf(hj * r);
                    aZ[i][j][q] = sigmoid_f(aZ[i][j][q] + bz[j]);
                }
    }
    __syncthreads();

    // --- phase 2: 16 k-steps (a @ U_h then mgn @ W_h), depth-2 B prefetch ---
    f32x4 aH[8][2];
    #pragma unroll
    for (int i = 0; i < 8; ++i)
        #pragma unroll
        for (int j = 0; j < 2; ++j)
            aH[i][j] = (f32x4){0.f, 0.f, 0.f, 0.f};

    {
        bf16x8 bHA[2], bHB[2];
        LOADB_H(0, bHA);
        LOADB_H(1, bHB);
        STEP_H(0, bHA);  LOADB_H(2, bHA);
        STEP_H(1, bHB);  LOADB_H(3, bHB);
        STEP_H(2, bHA);  LOADB_H(4, bHA);
        STEP_H(3, bHB);  LOADB_H(5, bHB);
        STEP_H(4, bHA);  LOADB_H(6, bHA);
        STEP_H(5, bHB);  LOADB_H(7, bHB);
        STEP_H(6, bHA);  LOADB_H(8, bHA);
        STEP_H(7, bHB);  LOADB_H(9, bHB);
        STEP_H(8, bHA);  LOADB_H(10, bHA);
        STEP_H(9, bHB);  LOADB_H(11, bHB);
        STEP_H(10, bHA); LOADB_H(12, bHA);
        STEP_H(11, bHB); LOADB_H(13, bHB);
        STEP_H(12, bHA); LOADB_H(14, bHA);
        STEP_H(13, bHB); LOADB_H(15, bHB);
        STEP_H(14, bHA);
        STEP_H(15, bHB);
    }

    // --- epilogue: out = ht + z*(h - ht), h re-read f32 (L3-warm) ---
    {
        float bh[2];
        #pragma unroll
        for (int j = 0; j < 2; ++j) bh[j] = bh_[colbase + j * 16 + l15];
        #pragma unroll
        for (int i = 0; i < 8; ++i)
            #pragma unroll
            for (int j = 0; j < 2; ++j)
                #pragma unroll
                for (int q = 0; q < 4; ++q) {
                    const int row = i * 16 + kq * 4 + q;
                    const int c   = colbase + j * 16 + l15;
                    const float ht = tanh_f(aH[i][j][q] + bh[j]);
                    const float z  = aZ[i][j][q];
                    const float h  = joint[(r0 + row) * H + c];
                    out[(r0 + row) * H + c] = ht + z * (h - ht);
                }
    }
}

extern "C" void kernel_launch(void* const* d_in, const int* in_sizes, int n_in,
                              void* d_out, int out_size, void* d_ws, size_t ws_size,
                              hipStream_t stream)
{
    const float* joint = (const float*)d_in[0];
    const float* mgn   = (const float*)d_in[1];
    const float* Wr    = (const float*)d_in[2];
    const float* Wz    = (const float*)d_in[3];
    const float* Wh    = (const float*)d_in[4];
    const float* Ur    = (const float*)d_in[5];
    const float* Uz    = (const float*)d_in[6];
    const float* Uh    = (const float*)d_in[7];
    const float* br    = (const float*)d_in[8];
    const float* bz    = (const float*)d_in[9];
    const float* bh    = (const float*)d_in[10];

    ushort* P  = (ushort*)d_ws;          // 786 KB scratch
    float* out = (float*)d_out;

    prep_w<<<512, 256, 0, stream>>>(Wr, Wz, Wh, Ur, Uz, Uh, P);

    const int nrows = 65536;
    gru_main<<<nrows / BM, NTHR, 0, stream>>>(joint, mgn, P, br, bz, bh, out);
}

// Round 11
// 99.948 us; speedup vs baseline: 1.3736x; 1.1881x over previous
//
#include <hip/hip_runtime.h>

#define H     256
#define BM    128
#define NTHR  1024
#define LDK2  264    // 256 + 8 pad (ushorts): row stride 528 B

typedef __attribute__((ext_vector_type(4))) float f32x4;
typedef __attribute__((ext_vector_type(8))) short bf16x8;

__device__ __forceinline__ ushort f2bf(float f) {
    union { float f; unsigned u; } v; v.f = f;
    unsigned u = v.u;
    unsigned r = (u + 0x7fffu + ((u >> 16) & 1u)) >> 16;
    return (ushort)r;
}
__device__ __forceinline__ float bf2f(ushort h) {
    union { unsigned u; float f; } v; v.u = ((unsigned)h) << 16;
    return v.f;
}
__device__ __forceinline__ float sigmoid_f(float x) {
    return __builtin_amdgcn_rcpf(1.0f + __expf(-x));
}
__device__ __forceinline__ float tanh_f(float x) {
    float ax = fabsf(x);
    float e  = __expf(-2.0f * ax);
    float t  = (1.0f - e) * __builtin_amdgcn_rcpf(1.0f + e);
    return copysignf(t, x);
}

// --- weight prep: f32 [k][n] -> bf16 panels [n][k] in d_ws ---
// rows 0..255 = r cols (k<256: W_r, k>=256: U_r); 256..511 = z; 512..767 = h
__global__ void prep_w(const float* __restrict__ Wr, const float* __restrict__ Wz,
                       const float* __restrict__ Wh, const float* __restrict__ Ur,
                       const float* __restrict__ Uz, const float* __restrict__ Uh,
                       ushort* __restrict__ P)
{
    const int k  = blockIdx.x;          // 0..511
    const int kk = k & 255;
    const bool hi = k >= 256;
    for (int n = threadIdx.x; n < 768; n += 256) {
        float v;
        if (n < 256)      v = (hi ? Ur : Wr)[kk * 256 + n];
        else if (n < 512) v = (hi ? Uz : Wz)[kk * 256 + (n - 256)];
        else              v = (hi ? Uh : Wh)[kk * 256 + (n - 512)];
        P[(size_t)n * 512 + k] = f2bf(v);
    }
}

#define MFMA(a, b, c) __builtin_amdgcn_mfma_f32_16x16x32_bf16((a), (b), (c), 0, 0, 0)

// ---- phase-1 (r|z): step S in [0,16); S<8 -> sb0/W, S>=8 -> sb1/U.  One B-frag per gate.
#define LOADB_RZ(S, BR, BZ) do {                                              \
    const int ko_ = (((S) < 8) ? 0 : 256) + ((S) & 7) * 32;                   \
    BR = *(const bf16x8*)(pBr + ko_);                                         \
    BZ = *(const bf16x8*)(pBz + ko_);                                         \
} while (0)

#define STEP_RZ(S, BR, BZ) do {                                               \
    const ushort* sb_ = ((S) < 8) ? sb0 : sb1;                                \
    const int k0_ = ((S) & 7) * 32;                                           \
    bf16x8 af_[4];                                                            \
    _Pragma("unroll") for (int i_ = 0; i_ < 4; ++i_)                          \
        af_[i_] = *(const bf16x8*)&sb_[(i_ * 16 + l15) * LDK2 + k0_ + kq * 8];\
    _Pragma("unroll") for (int i_ = 0; i_ < 4; ++i_) {                        \
        aR[i_] = MFMA(af_[i_], BR, aR[i_]);                                   \
        aZ[i_] = MFMA(af_[i_], BZ, aZ[i_]);                                   \
    }                                                                         \
    _Pragma("unroll") for (int i_ = 0; i_ < 4; ++i_)                          \
        af_[i_] = *(const bf16x8*)&sb_[((i_ + 4) * 16 + l15) * LDK2 + k0_ + kq * 8]; \
    _Pragma("unroll") for (int i_ = 0; i_ < 4; ++i_) {                        \
        aR[i_ + 4] = MFMA(af_[i_], BR, aR[i_ + 4]);                           \
        aZ[i_ + 4] = MFMA(af_[i_], BZ, aZ[i_ + 4]);                           \
    }                                                                         \
} while (0)

// ---- phase-2 (h): S<8 -> sb1/U_h (a), S>=8 -> sb0/W_h (mgn)
#define LOADB_H(S, BH) do {                                                   \
    const int ko_ = (((S) < 8) ? 256 : 0) + ((S) & 7) * 32;                   \
    BH = *(const bf16x8*)(pBh + ko_);                                         \
} while (0)

#define STEP_H(S, BH) do {                                                    \
    const ushort* sb_ = ((S) < 8) ? sb1 : sb0;                                \
    const int k0_ = ((S) & 7) * 32;                                           \
    bf16x8 af_[4];                                                            \
    _Pragma("unroll") for (int i_ = 0; i_ < 4; ++i_)                          \
        af_[i_] = *(const bf16x8*)&sb_[(i_ * 16 + l15) * LDK2 + k0_ + kq * 8];\
    _Pragma("unroll") for (int i_ = 0; i_ < 4; ++i_)                          \
        aH[i_] = MFMA(af_[i_], BH, aH[i_]);                                   \
    _Pragma("unroll") for (int i_ = 0; i_ < 4; ++i_)                          \
        af_[i_] = *(const bf16x8*)&sb_[((i_ + 4) * 16 + l15) * LDK2 + k0_ + kq * 8]; \
    _Pragma("unroll") for (int i_ = 0; i_ < 4; ++i_)                          \
        aH[i_ + 4] = MFMA(af_[i_], BH, aH[i_ + 4]);                           \
} while (0)

// ---- joint staging: 2-f32x4 chunks (8 regs), load early / commit ~2 k-steps later
#define LOADJ(CI) do {                                                        \
    _Pragma("unroll") for (int i_ = 0; i_ < 2; ++i_) {                        \
        const int c_ = tid + ((CI) * 2 + i_) * NTHR;                          \
        jv[i_] = *(const f32x4*)(joint + (r0 + (c_ >> 6)) * H + (c_ & 63) * 4); \
    }                                                                         \
} while (0)

#define COMMITJ(CI) do {                                                      \
    _Pragma("unroll") for (int i_ = 0; i_ < 2; ++i_) {                        \
        const int c_ = tid + ((CI) * 2 + i_) * NTHR;                          \
        ushort4 w_;                                                           \
        w_.x = f2bf(jv[i_][0]); w_.y = f2bf(jv[i_][1]);                       \
        w_.z = f2bf(jv[i_][2]); w_.w = f2bf(jv[i_][3]);                       \
        *(ushort4*)&sb1[(c_ >> 6) * LDK2 + (c_ & 63) * 4] = w_;               \
    }                                                                         \
} while (0)

__global__ __launch_bounds__(NTHR, 4)
void gru_main(const float* __restrict__ joint, const float* __restrict__ mgn,
              const ushort* __restrict__ P,
              const float* __restrict__ br_, const float* __restrict__ bz_,
              const float* __restrict__ bh_, float* __restrict__ out)
{
    __shared__ ushort sb0[BM * LDK2];   // mgn bf16 — resident whole kernel
    __shared__ ushort sb1[BM * LDK2];   // joint bf16 -> overwritten by a = joint*r

    const int tid  = threadIdx.x;
    const int wave = tid >> 6;          // 0..15
    const int lane = tid & 63;
    const int l15  = lane & 15;
    const int kq   = lane >> 4;         // 0..3
    const int colbase = wave * 16;      // wave tile: 128 rows x 16 cols -> B read once
    const int col  = colbase + l15;
    const size_t r0 = (size_t)blockIdx.x * BM;

    const ushort* __restrict__ pBr = P + (size_t)col * 512 + kq * 8;
    const ushort* __restrict__ pBz = pBr + (size_t)256 * 512;
    const ushort* __restrict__ pBh = pBr + (size_t)512 * 512;

    // --- stage 0: mgn -> sb0 ---
    #pragma unroll
    for (int i = 0; i < 8; ++i) {
        const int c   = tid + i * NTHR;
        const int row = c >> 6;
        const int c4  = (c & 63) * 4;
        const f32x4 v = *(const f32x4*)(mgn + (r0 + row) * H + c4);
        ushort4 w;
        w.x = f2bf(v[0]); w.y = f2bf(v[1]); w.z = f2bf(v[2]); w.w = f2bf(v[3]);
        *(ushort4*)&sb0[row * LDK2 + c4] = w;
    }
    __syncthreads();

    f32x4 aR[8], aZ[8];
    #pragma unroll
    for (int i = 0; i < 8; ++i) {
        aR[i] = (f32x4){0.f, 0.f, 0.f, 0.f};
        aZ[i] = (f32x4){0.f, 0.f, 0.f, 0.f};
    }

    // --- phase 1: 16 k-steps, depth-2 rolling B prefetch; joint->sb1 in 4 chunks ---
    {
        f32x4 jv[2];
        bf16x8 bRA, bZA, bRB, bZB;
        LOADB_RZ(0, bRA, bZA);
        LOADB_RZ(1, bRB, bZB);
        LOADJ(0);
        STEP_RZ(0, bRA, bZA);  LOADB_RZ(2, bRA, bZA);
        STEP_RZ(1, bRB, bZB);  LOADB_RZ(3, bRB, bZB);
        COMMITJ(0); LOADJ(1);
        STEP_RZ(2, bRA, bZA);  LOADB_RZ(4, bRA, bZA);
        STEP_RZ(3, bRB, bZB);  LOADB_RZ(5, bRB, bZB);
        COMMITJ(1); LOADJ(2);
        STEP_RZ(4, bRA, bZA);  LOADB_RZ(6, bRA, bZA);
        STEP_RZ(5, bRB, bZB);  LOADB_RZ(7, bRB, bZB);
        COMMITJ(2); LOADJ(3);
        STEP_RZ(6, bRA, bZA);  LOADB_RZ(8, bRA, bZA);
        STEP_RZ(7, bRB, bZB);  LOADB_RZ(9, bRB, bZB);
        COMMITJ(3);
        __syncthreads();        // sb1 (joint) fully staged; sb0 untouched
        STEP_RZ(8, bRA, bZA);  LOADB_RZ(10, bRA, bZA);
        STEP_RZ(9, bRB, bZB);  LOADB_RZ(11, bRB, bZB);
        STEP_RZ(10, bRA, bZA); LOADB_RZ(12, bRA, bZA);
        STEP_RZ(11, bRB, bZB); LOADB_RZ(13, bRB, bZB);
        STEP_RZ(12, bRA, bZA); LOADB_RZ(14, bRA, bZA);
        STEP_RZ(13, bRB, bZB); LOADB_RZ(15, bRB, bZB);
        STEP_RZ(14, bRA, bZA);
        STEP_RZ(15, bRB, bZB);
    }
    __syncthreads();

    // --- gates: r -> a (overwrite sb1); z -> aZ; h saved to regs as bf16 ---
    uint hs[16];
    {
        const float br = br_[col];
        const float bz = bz_[col];
        #pragma unroll
        for (int i = 0; i < 8; ++i) {
            ushort hb[4];
            #pragma unroll
            for (int q = 0; q < 4; ++q) {
                const int row = i * 16 + kq * 4 + q;
                const int idx = row * LDK2 + col;
                const float r = sigmoid_f(aR[i][q] + br);
                hb[q] = sb1[idx];
                sb1[idx] = f2bf(bf2f(hb[q]) * r);
                aZ[i][q] = sigmoid_f(aZ[i][q] + bz);
            }
            hs[i * 2 + 0] = (uint)hb[0] | ((uint)hb[1] << 16);
            hs[i * 2 + 1] = (uint)hb[2] | ((uint)hb[3] << 16);
        }
    }
    __syncthreads();

    // --- phase 2: 16 k-steps (a @ U_h then mgn @ W_h), depth-2 B prefetch ---
    f32x4 aH[8];
    #pragma unroll
    for (int i = 0; i < 8; ++i) aH[i] = (f32x4){0.f, 0.f, 0.f, 0.f};

    {
        bf16x8 bHA, bHB;
        LOADB_H(0, bHA);
        LOADB_H(1, bHB);
        STEP_H(0, bHA);  LOADB_H(2, bHA);
        STEP_H(1, bHB);  LOADB_H(3, bHB);
        STEP_H(2, bHA);  LOADB_H(4, bHA);
        STEP_H(3, bHB);  LOADB_H(5, bHB);
        STEP_H(4, bHA);  LOADB_H(6, bHA);
        STEP_H(5, bHB);  LOADB_H(7, bHB);
        STEP_H(6, bHA);  LOADB_H(8, bHA);
        STEP_H(7, bHB);  LOADB_H(9, bHB);
        STEP_H(8, bHA);  LOADB_H(10, bHA);
        STEP_H(9, bHB);  LOADB_H(11, bHB);
        STEP_H(10, bHA); LOADB_H(12, bHA);
        STEP_H(11, bHB); LOADB_H(13, bHB);
        STEP_H(12, bHA); LOADB_H(14, bHA);
        STEP_H(13, bHB); LOADB_H(15, bHB);
        STEP_H(14, bHA);
        STEP_H(15, bHB);
    }

    // --- epilogue: out = ht + z*(h - ht); h from registers (bf16), no re-read ---
    {
        const float bh = bh_[col];
        #pragma unroll
        for (int i = 0; i < 8; ++i)
            #pragma unroll
            for (int q = 0; q < 4; ++q) {
                const int row = i * 16 + kq * 4 + q;
                const float ht = tanh_f(aH[i][q] + bh);
                const float z  = aZ[i][q];
                const float h  = bf2f((ushort)(hs[i * 2 + (q >> 1)] >> ((q & 1) * 16)));
                out[(r0 + row) * H + col] = ht + z * (h - ht);
            }
    }
}

extern "C" void kernel_launch(void* const* d_in, const int* in_sizes, int n_in,
                              void* d_out, int out_size, void* d_ws, size_t ws_size,
                              hipStream_t stream)
{
    const float* joint = (const float*)d_in[0];
    const float* mgn   = (const float*)d_in[1];
    const float* Wr    = (const float*)d_in[2];
    const float* Wz    = (const float*)d_in[3];
    const float* Wh    = (const float*)d_in[4];
    const float* Ur    = (const float*)d_in[5];
    const float* Uz    = (const float*)d_in[6];
    const float* Uh    = (const float*)d_in[7];
    const float* br    = (const float*)d_in[8];
    const float* bz    = (const float*)d_in[9];
    const float* bh    = (const float*)d_in[10];

    ushort* P  = (ushort*)d_ws;          // 786 KB scratch
    float* out = (float*)d_out;

    prep_w<<<512, 256, 0, stream>>>(Wr, Wz, Wh, Ur, Uz, Uh, P);

    const int nrows = 65536;
    gru_main<<<nrows / BM, NTHR, 0, stream>>>(joint, mgn, P, br, bz, bh, out);
}